// Round 2
// baseline (147.791 us; speedup 1.0000x reference)
//
#include <hip/hip_runtime.h>
#include <math.h>

#define Bn 2
#define Nn 384
#define Cc 16
#define Hh 64
#define NBk 10
#define NT 32                 // n-tile per conv block
#define NTILES (Nn/NT)        // 12
#define MCH 48                // m-chunks
#define MB (Nn/MCH)           // 8
#define BNC (Bn*Nn*Cc)        // 12288
#define SCALE 0.05103103630798288f   // 1/sqrt(384)
#define CP_N (MCH*NTILES*Bn*Cc)      // 18432

// W2x[b,m,h,i] = sum_j w2[h, i*16+j] * x_masked[b,m,j]
__global__ __launch_bounds__(256) void k_w2x_from_x(
    const float* __restrict__ x, const int* __restrict__ mask,
    const float* __restrict__ w2, float* __restrict__ w2x)
{
    __shared__ float xs[Cc];
    const int bm = blockIdx.x;           // b*N + m
    const int b = bm / Nn, m = bm % Nn;
    const int tid = threadIdx.x;
    if (tid < Cc) {
        int keep = mask[(size_t)b*Nn*Nn + (size_t)m*Nn + m];
        xs[tid] = keep ? x[(size_t)bm*Cc + tid] : 0.0f;
    }
    __syncthreads();
    const int h = tid >> 2, ig = tid & 3;
    float oc[4];
    #pragma unroll
    for (int c = 0; c < 4; ++c) {
        const int i = ig*4 + c;
        float acc = 0.f;
        #pragma unroll
        for (int jg = 0; jg < 4; ++jg) {
            float4 wv = *reinterpret_cast<const float4*>(w2 + h*256 + i*16 + jg*4);
            acc += wv.x*xs[jg*4+0] + wv.y*xs[jg*4+1] + wv.z*xs[jg*4+2] + wv.w*xs[jg*4+3];
        }
        oc[c] = acc;
    }
    float4 o; o.x=oc[0]; o.y=oc[1]; o.z=oc[2]; o.w=oc[3];
    *reinterpret_cast<float4*>(w2x + (size_t)bm*(Hh*Cc) + tid*4) = o;
}

// same, but xin[b,m,j] = sum over m-chunks of part (conv1 output)
__global__ __launch_bounds__(256) void k_w2x_from_part(
    const float* __restrict__ part, const float* __restrict__ w2, float* __restrict__ w2x)
{
    __shared__ float ps[16*16];
    __shared__ float xs[Cc];
    const int bm = blockIdx.x;
    const int tid = threadIdx.x;
    const int i = tid & 15, g = tid >> 4;   // 16 groups x 3 chunks each
    {
        float s = 0.f;
        #pragma unroll
        for (int c = 0; c < 3; ++c)
            s += part[(size_t)(g*3 + c)*BNC + (size_t)bm*Cc + i];
        ps[g*16 + i] = s;
    }
    __syncthreads();
    if (tid < Cc) {
        float s = 0.f;
        #pragma unroll
        for (int gg = 0; gg < 16; ++gg) s += ps[gg*16 + tid];
        xs[tid] = s;
    }
    __syncthreads();
    const int h = tid >> 2, ig = tid & 3;
    float oc[4];
    #pragma unroll
    for (int c = 0; c < 4; ++c) {
        const int ii = ig*4 + c;
        float acc = 0.f;
        #pragma unroll
        for (int jg = 0; jg < 4; ++jg) {
            float4 wv = *reinterpret_cast<const float4*>(w2 + h*256 + ii*16 + jg*4);
            acc += wv.x*xs[jg*4+0] + wv.y*xs[jg*4+1] + wv.z*xs[jg*4+2] + wv.w*xs[jg*4+3];
        }
        oc[c] = acc;
    }
    float4 o; o.x=oc[0]; o.y=oc[1]; o.z=oc[2]; o.w=oc[3];
    *reinterpret_cast<float4*>(w2x + (size_t)bm*(Hh*Cc) + tid*4) = o;
}

// conv: out[b,n,i] partials over an m-chunk. No in-loop LDS, no in-loop barriers.
// FINAL=false: write per-chunk rows to part. FINAL=true: mask + column-sum -> colpart.
template<bool FINAL>
__global__ __launch_bounds__(256, 3) void k_conv(
    const float* __restrict__ xyz, const float* __restrict__ w1,
    const float* __restrict__ w2x, const int* __restrict__ mask,
    float* __restrict__ out)
{
    __shared__ float red[8*544];   // [hg][ns*17+i], pad 17 -> conflict-free

    const int tid = threadIdx.x;
    const int ns = tid & 31;           // n slot
    const int hg = tid >> 5;           // h group (0..7)
    const int h0 = hg * 8;
    const int b  = blockIdx.z;
    const int n0 = blockIdx.y * NT;
    const int m0 = blockIdx.x * MB;
    const int ch = blockIdx.x;

    const float* xyzb = xyz + (size_t)b*Nn*3;
    const float xn0 = xyzb[(n0+ns)*3+0];
    const float xn1 = xyzb[(n0+ns)*3+1];
    const float xn2 = xyzb[(n0+ns)*3+2];

    // w1 slice for this thread's 8 h's, in registers (80 floats)
    float4 w1a[NBk], w1b[NBk];
    #pragma unroll
    for (int k = 0; k < NBk; ++k) {
        w1a[k] = *reinterpret_cast<const float4*>(w1 + k*Hh + h0);
        w1b[k] = *reinterpret_cast<const float4*>(w1 + k*Hh + h0 + 4);
    }

    float acc[Cc];
    #pragma unroll
    for (int i = 0; i < Cc; ++i) acc[i] = 0.f;

    const float* w2xb = w2x + (size_t)(b*Nn + m0)*(Hh*Cc);

    for (int mi = 0; mi < MB; ++mi) {
        const float xm0 = xyzb[(m0+mi)*3+0];   // block-uniform -> s_load
        const float xm1 = xyzb[(m0+mi)*3+1];
        const float xm2 = xyzb[(m0+mi)*3+2];
        const float dx = xn0-xm0, dy = xn1-xm1, dz = xn2-xm2;
        const float r = sqrtf(dx*dx + dy*dy + dz*dz + 1e-12f);

        float hid[8];
        #pragma unroll
        for (int j = 0; j < 8; ++j) hid[j] = 0.f;
        #pragma unroll
        for (int k = 0; k < NBk; ++k) {
            const float u = r - (float)k * (10.0f/9.0f);
            const float e = __expf(-u*u);
            hid[0] += e*w1a[k].x; hid[1] += e*w1a[k].y;
            hid[2] += e*w1a[k].z; hid[3] += e*w1a[k].w;
            hid[4] += e*w1b[k].x; hid[5] += e*w1b[k].y;
            hid[6] += e*w1b[k].z; hid[7] += e*w1b[k].w;
        }

        const float* wrow = w2xb + (size_t)mi*(Hh*Cc);
        #pragma unroll
        for (int j = 0; j < 8; ++j) {
            const float v = hid[j];
            const float sj = v * __builtin_amdgcn_rcpf(1.0f + __expf(-v));  // swish
            const float4* wp = reinterpret_cast<const float4*>(wrow + (h0+j)*Cc);
            const float4 q0 = wp[0], q1 = wp[1], q2 = wp[2], q3 = wp[3];
            acc[0] += sj*q0.x; acc[1] += sj*q0.y; acc[2] += sj*q0.z; acc[3] += sj*q0.w;
            acc[4] += sj*q1.x; acc[5] += sj*q1.y; acc[6] += sj*q1.z; acc[7] += sj*q1.w;
            acc[8] += sj*q2.x; acc[9] += sj*q2.y; acc[10]+= sj*q2.z; acc[11]+= sj*q2.w;
            acc[12]+= sj*q3.x; acc[13]+= sj*q3.y; acc[14]+= sj*q3.z; acc[15]+= sj*q3.w;
        }
    }

    // cross-h-group reduce via padded LDS
    #pragma unroll
    for (int i = 0; i < Cc; ++i) red[hg*544 + ns*17 + i] = acc[i];
    __syncthreads();

    if (!FINAL) {
        #pragma unroll
        for (int it = 0; it < 2; ++it) {
            const int o = it*256 + tid;
            const int nn = o >> 4, i = o & 15;
            float s = 0.f;
            #pragma unroll
            for (int g = 0; g < 8; ++g) s += red[g*544 + nn*17 + i];
            out[(((size_t)ch*Bn + b)*Nn + (n0+nn))*Cc + i] = s * SCALE;
        }
    } else {
        #pragma unroll
        for (int it = 0; it < 2; ++it) {
            const int o = it*256 + tid;
            const int nn = o & 31, i = o >> 5;
            float s = 0.f;
            #pragma unroll
            for (int g = 0; g < 8; ++g) s += red[g*544 + nn*17 + i];
            s *= SCALE;
            const int gn = n0 + nn;
            const int keep = mask[((size_t)b*Nn + gn)*Nn + gn];
            float v = keep ? s : 0.f;
            #pragma unroll
            for (int d = 1; d < 32; d <<= 1) v += __shfl_xor(v, d, 32);
            if (nn == 0)
                out[((size_t)ch*NTILES + blockIdx.y)*(Bn*Cc) + b*Cc + i] = v;
        }
    }
}

// colpart[576][b*16+i] -> colsum -> normalize (ddof=1) -> @fc2^T -> softmax
__global__ __launch_bounds__(256) void k_finalize(
    const float* __restrict__ colpart, const float* __restrict__ fc2, float* __restrict__ out)
{
    __shared__ float redf[256];
    const int tid = threadIdx.x;
    float s = 0.f;
    for (int base = tid; base < CP_N; base += 256) s += colpart[base];  // bi = tid&31 invariant
    redf[tid] = s;
    __syncthreads();
    if (tid < 32) {
        float v = 0.f;
        #pragma unroll
        for (int g = 0; g < 8; ++g) v += redf[g*32 + tid];
        // lanes 0-15: b=0, lanes 16-31: b=1; i = tid&15
        const int i = tid & 15;
        float sum = v;
        #pragma unroll
        for (int d = 1; d < 16; d <<= 1) sum += __shfl_xor(sum, d, 32);
        const float mean = sum * (1.0f/16.0f);
        const float c0 = v - mean;
        float vs = c0*c0;
        #pragma unroll
        for (int d = 1; d < 16; d <<= 1) vs += __shfl_xor(vs, d, 32);
        const float nv = c0 / (sqrtf(vs * (1.0f/15.0f)) + 1e-6f);  // std ddof=1 + eps
        float y = 0.f;
        #pragma unroll
        for (int j = 0; j < 16; ++j) {
            float nj = __shfl(nv, (tid & 16) + j, 32);
            y += nj * fc2[i*16 + j];
        }
        float mx = y;
        #pragma unroll
        for (int d = 1; d < 16; d <<= 1) mx = fmaxf(mx, __shfl_xor(mx, d, 32));
        const float e = __expf(y - mx);
        float es = e;
        #pragma unroll
        for (int d = 1; d < 16; d <<= 1) es += __shfl_xor(es, d, 32);
        out[(tid >> 4)*Cc + i] = e / es;
    }
}

extern "C" void kernel_launch(void* const* d_in, const int* in_sizes, int n_in,
                              void* d_out, int out_size, void* d_ws, size_t ws_size,
                              hipStream_t stream) {
    const float* x    = (const float*)d_in[0];
    const float* xyz  = (const float*)d_in[1];
    const int*   mask = (const int*)  d_in[2];
    const float* c1w1 = (const float*)d_in[3];
    const float* c1w2 = (const float*)d_in[4];
    const float* c2w1 = (const float*)d_in[5];
    const float* c2w2 = (const float*)d_in[6];
    const float* fc2  = (const float*)d_in[7];
    float* out = (float*)d_out;

    float* A  = (float*)d_ws;                       // W2x: B*N*H*C = 786432 floats
    float* P  = A + (size_t)Bn*Nn*Hh*Cc;            // part: MCH*B*N*C = 589824 floats
    float* CP = P + (size_t)MCH*BNC;                // colpart: 18432 floats

    dim3 gconv(MCH, NTILES, Bn);

    k_w2x_from_x   <<<Bn*Nn, 256, 0, stream>>>(x, mask, c1w2, A);
    k_conv<false>  <<<gconv, 256, 0, stream>>>(xyz, c1w1, A, mask, P);
    k_w2x_from_part<<<Bn*Nn, 256, 0, stream>>>(P, c2w2, A);
    k_conv<true>   <<<gconv, 256, 0, stream>>>(xyz, c2w1, A, mask, CP);
    k_finalize     <<<1, 256, 0, stream>>>(CP, fc2, out);
}

// Round 3
// 89.277 us; speedup vs baseline: 1.6554x; 1.6554x over previous
//
#include <hip/hip_runtime.h>
#include <hip/hip_fp16.h>
#include <math.h>

#define Bn 2
#define Nn 384
#define Cc 16
#define Hh 64
#define NBk 10
#define NT 32                 // n-tile per conv block
#define NTILES (Nn/NT)        // 12
#define MCH1 64               // m-chunks conv1
#define MB1 (Nn/MCH1)         // 6
#define MCH2 96               // m-chunks conv2
#define MB2 (Nn/MCH2)         // 4
#define BNC (Bn*Nn*Cc)        // 12288
#define SCALE 0.05103103630798288f   // 1/sqrt(384)
#define CP_N (MCH2*NTILES*Bn*Cc)     // 36864

__device__ __forceinline__ void gload_lds16(const float* g, float* l) {
    __builtin_amdgcn_global_load_lds((const __attribute__((address_space(1))) void*)g,
                                     (__attribute__((address_space(3))) void*)l, 16, 0, 0);
}

// W2x[b,m,h,i] = sum_j w2[h, i*16+j] * x_masked[b,m,j]
__global__ __launch_bounds__(256) void k_w2x_from_x(
    const float* __restrict__ x, const int* __restrict__ mask,
    const float* __restrict__ w2, float* __restrict__ w2x)
{
    __shared__ float xs[Cc];
    const int bm = blockIdx.x;           // b*N + m
    const int b = bm / Nn, m = bm % Nn;
    const int tid = threadIdx.x;
    if (tid < Cc) {
        int keep = mask[(size_t)b*Nn*Nn + (size_t)m*Nn + m];
        xs[tid] = keep ? x[(size_t)bm*Cc + tid] : 0.0f;
    }
    __syncthreads();
    const int h = tid >> 2, ig = tid & 3;
    float oc[4];
    #pragma unroll
    for (int c = 0; c < 4; ++c) {
        const int i = ig*4 + c;
        float acc = 0.f;
        #pragma unroll
        for (int jg = 0; jg < 4; ++jg) {
            float4 wv = *reinterpret_cast<const float4*>(w2 + h*256 + i*16 + jg*4);
            acc += wv.x*xs[jg*4+0] + wv.y*xs[jg*4+1] + wv.z*xs[jg*4+2] + wv.w*xs[jg*4+3];
        }
        oc[c] = acc;
    }
    float4 o; o.x=oc[0]; o.y=oc[1]; o.z=oc[2]; o.w=oc[3];
    *reinterpret_cast<float4*>(w2x + (size_t)bm*(Hh*Cc) + tid*4) = o;
}

// xin[b,m,j] = sum over MCH1 chunks of fp16 part (conv1 output)
__global__ __launch_bounds__(256) void k_w2x_from_part(
    const __half* __restrict__ part, const float* __restrict__ w2, float* __restrict__ w2x)
{
    __shared__ float ps[16*16];
    __shared__ float xs[Cc];
    const int bm = blockIdx.x;
    const int tid = threadIdx.x;
    const int i = tid & 15, g = tid >> 4;   // 16 groups x 4 chunks each
    {
        float s = 0.f;
        #pragma unroll
        for (int c = 0; c < MCH1/16; ++c)
            s += __half2float(part[(size_t)(g*(MCH1/16) + c)*BNC + (size_t)bm*Cc + i]);
        ps[g*16 + i] = s;
    }
    __syncthreads();
    if (tid < Cc) {
        float s = 0.f;
        #pragma unroll
        for (int gg = 0; gg < 16; ++gg) s += ps[gg*16 + tid];
        xs[tid] = s;
    }
    __syncthreads();
    const int h = tid >> 2, ig = tid & 3;
    float oc[4];
    #pragma unroll
    for (int c = 0; c < 4; ++c) {
        const int ii = ig*4 + c;
        float acc = 0.f;
        #pragma unroll
        for (int jg = 0; jg < 4; ++jg) {
            float4 wv = *reinterpret_cast<const float4*>(w2 + h*256 + ii*16 + jg*4);
            acc += wv.x*xs[jg*4+0] + wv.y*xs[jg*4+1] + wv.z*xs[jg*4+2] + wv.w*xs[jg*4+3];
        }
        oc[c] = acc;
    }
    float4 o; o.x=oc[0]; o.y=oc[1]; o.z=oc[2]; o.w=oc[3];
    *reinterpret_cast<float4*>(w2x + (size_t)bm*(Hh*Cc) + tid*4) = o;
}

// conv over an m-chunk of MBt m's; 2-phase async LDS double-buffer for W2x tiles.
// FINAL=false: per-chunk fp16 rows -> parth. FINAL=true: mask + column-sum -> colpart (fp32).
template<int MBt, bool FINAL>
__global__ __launch_bounds__(256, 6) void k_conv(
    const float* __restrict__ xyz, const float* __restrict__ w1,
    const float* __restrict__ w2x, const int* __restrict__ mask,
    __half* __restrict__ parth, float* __restrict__ colpart)
{
    __shared__ float w1s[NBk*Hh];        // 2.5 KB
    __shared__ float dbuf[2][Hh*Cc];     // 8 KB
    __shared__ float red[4*32*17];       // 8.5 KB

    const int tid = threadIdx.x;
    const int ns = tid & 31;           // n slot
    const int hg = tid >> 5;           // h group (0..7)
    const int h0 = hg * 8;
    const int wv = tid >> 6;           // wave 0..3
    const int b  = blockIdx.z;
    const int n0 = blockIdx.y * NT;
    const int m0 = blockIdx.x * MBt;
    const int ch = blockIdx.x;

    for (int idx = tid; idx < NBk*Hh; idx += 256) w1s[idx] = w1[idx];

    const float* xyzb = xyz + (size_t)b*Nn*3;
    const float xn0 = xyzb[(n0+ns)*3+0];
    const float xn1 = xyzb[(n0+ns)*3+1];
    const float xn2 = xyzb[(n0+ns)*3+2];

    const float* w2xb = w2x + (size_t)(b*Nn + m0)*(Hh*Cc);

    // prologue: stage m0 tile into dbuf[0]
    gload_lds16(w2xb + tid*4, &dbuf[0][wv*256]);
    __syncthreads();

    float acc[Cc];
    #pragma unroll
    for (int i = 0; i < Cc; ++i) acc[i] = 0.f;

    int cur = 0;
    for (int mi = 0; mi < MBt; ++mi) {
        if (mi + 1 < MBt)   // issue next tile's loads (hidden under compute)
            gload_lds16(w2xb + (size_t)(mi+1)*(Hh*Cc) + tid*4, &dbuf[cur^1][wv*256]);

        const float xm0 = xyzb[(m0+mi)*3+0];   // block-uniform
        const float xm1 = xyzb[(m0+mi)*3+1];
        const float xm2 = xyzb[(m0+mi)*3+2];
        const float dx = xn0-xm0, dy = xn1-xm1, dz = xn2-xm2;
        const float r = sqrtf(dx*dx + dy*dy + dz*dz + 1e-12f);

        float hid[8];
        #pragma unroll
        for (int j = 0; j < 8; ++j) hid[j] = 0.f;
        #pragma unroll
        for (int k = 0; k < NBk; ++k) {
            const float u = r - (float)k * (10.0f/9.0f);
            const float e = __expf(-u*u);
            const float4* wk = reinterpret_cast<const float4*>(&w1s[k*Hh + h0]);
            const float4 a = wk[0], c = wk[1];
            hid[0] += e*a.x; hid[1] += e*a.y; hid[2] += e*a.z; hid[3] += e*a.w;
            hid[4] += e*c.x; hid[5] += e*c.y; hid[6] += e*c.z; hid[7] += e*c.w;
        }

        const float* wrow = &dbuf[cur][0];
        #pragma unroll
        for (int j = 0; j < 8; ++j) {
            const float v = hid[j];
            const float sj = v * __builtin_amdgcn_rcpf(1.0f + __expf(-v));  // swish
            const float4* wp = reinterpret_cast<const float4*>(wrow + (h0+j)*Cc);
            const float4 q0 = wp[0], q1 = wp[1], q2 = wp[2], q3 = wp[3];
            acc[0] += sj*q0.x; acc[1] += sj*q0.y; acc[2] += sj*q0.z; acc[3] += sj*q0.w;
            acc[4] += sj*q1.x; acc[5] += sj*q1.y; acc[6] += sj*q1.z; acc[7] += sj*q1.w;
            acc[8] += sj*q2.x; acc[9] += sj*q2.y; acc[10]+= sj*q2.z; acc[11]+= sj*q2.w;
            acc[12]+= sj*q3.x; acc[13]+= sj*q3.y; acc[14]+= sj*q3.z; acc[15]+= sj*q3.w;
        }
        __syncthreads();   // drains next-tile loads (vmcnt) + phase barrier
        cur ^= 1;
    }

    // reduce hg-pairs within wave (lane ^ 32), then 4 wave-partials via LDS
    #pragma unroll
    for (int i = 0; i < Cc; ++i) acc[i] += __shfl_xor(acc[i], 32, 64);
    if ((tid & 63) < 32) {
        #pragma unroll
        for (int i = 0; i < Cc; ++i) red[(wv*32 + ns)*17 + i] = acc[i];
    }
    __syncthreads();

    if (!FINAL) {
        #pragma unroll
        for (int it = 0; it < 2; ++it) {
            const int o = it*256 + tid;
            const int nn = o >> 4, i = o & 15;
            float s = 0.f;
            #pragma unroll
            for (int g = 0; g < 4; ++g) s += red[(g*32 + nn)*17 + i];
            parth[(((size_t)ch*Bn + b)*Nn + (n0+nn))*Cc + i] = __float2half(s * SCALE);
        }
    } else {
        #pragma unroll
        for (int it = 0; it < 2; ++it) {
            const int o = it*256 + tid;
            const int nn = o & 31, i = o >> 5;
            float s = 0.f;
            #pragma unroll
            for (int g = 0; g < 4; ++g) s += red[(g*32 + nn)*17 + i];
            s *= SCALE;
            const int gn = n0 + nn;
            const int keep = mask[((size_t)b*Nn + gn)*Nn + gn];
            float v = keep ? s : 0.f;
            #pragma unroll
            for (int d = 1; d < 32; d <<= 1) v += __shfl_xor(v, d, 32);
            if (nn == 0)
                colpart[((size_t)ch*NTILES + blockIdx.y)*(Bn*Cc) + b*Cc + i] = v;
        }
    }
}

// colpart -> colsum -> normalize (ddof=1) -> @fc2^T -> softmax
__global__ __launch_bounds__(256) void k_finalize(
    const float* __restrict__ colpart, const float* __restrict__ fc2, float* __restrict__ out)
{
    __shared__ float redf[1024];
    const int tid = threadIdx.x;
    float4 a; a.x = a.y = a.z = a.w = 0.f;
    for (int base = tid*4; base < CP_N; base += 1024) {
        float4 v = *reinterpret_cast<const float4*>(colpart + base);
        a.x += v.x; a.y += v.y; a.z += v.z; a.w += v.w;
    }
    *reinterpret_cast<float4*>(&redf[tid*4]) = a;
    __syncthreads();
    if (tid < 32) {
        float v = 0.f;                      // bin bi=tid : flat indices ≡ tid (mod 32)
        #pragma unroll
        for (int k = 0; k < 32; ++k) v += redf[tid + 32*k];
        const int i = tid & 15;             // lanes 0-15: b=0, 16-31: b=1
        float sum = v;
        #pragma unroll
        for (int d = 1; d < 16; d <<= 1) sum += __shfl_xor(sum, d, 32);
        const float mean = sum * (1.0f/16.0f);
        const float c0 = v - mean;
        float vs = c0*c0;
        #pragma unroll
        for (int d = 1; d < 16; d <<= 1) vs += __shfl_xor(vs, d, 32);
        const float nv = c0 / (sqrtf(vs * (1.0f/15.0f)) + 1e-6f);  // std ddof=1 + eps
        float y = 0.f;
        #pragma unroll
        for (int j = 0; j < 16; ++j) {
            float nj = __shfl(nv, (tid & 16) + j, 32);
            y += nj * fc2[i*16 + j];
        }
        float mx = y;
        #pragma unroll
        for (int d = 1; d < 16; d <<= 1) mx = fmaxf(mx, __shfl_xor(mx, d, 32));
        const float e = __expf(y - mx);
        float es = e;
        #pragma unroll
        for (int d = 1; d < 16; d <<= 1) es += __shfl_xor(es, d, 32);
        out[(tid >> 4)*Cc + i] = e / es;
    }
}

extern "C" void kernel_launch(void* const* d_in, const int* in_sizes, int n_in,
                              void* d_out, int out_size, void* d_ws, size_t ws_size,
                              hipStream_t stream) {
    const float* x    = (const float*)d_in[0];
    const float* xyz  = (const float*)d_in[1];
    const int*   mask = (const int*)  d_in[2];
    const float* c1w1 = (const float*)d_in[3];
    const float* c1w2 = (const float*)d_in[4];
    const float* c2w1 = (const float*)d_in[5];
    const float* c2w2 = (const float*)d_in[6];
    const float* fc2  = (const float*)d_in[7];
    float* out = (float*)d_out;

    float*  A  = (float*)d_ws;                         // W2x: 786432 f = 3.0 MB
    __half* P  = (__half*)(A + (size_t)Bn*Nn*Hh*Cc);   // fp16 partials: MCH1*BNC = 1.5 MB
    float*  CP = (float*)((char*)P + (size_t)MCH1*BNC*sizeof(__half)); // 36864 f = 144 KB

    dim3 g1(MCH1, NTILES, Bn);
    dim3 g2(MCH2, NTILES, Bn);

    k_w2x_from_x       <<<Bn*Nn, 256, 0, stream>>>(x, mask, c1w2, A);
    k_conv<MB1, false> <<<g1, 256, 0, stream>>>(xyz, c1w1, A, mask, P, CP);
    k_w2x_from_part    <<<Bn*Nn, 256, 0, stream>>>(P, c2w2, A);
    k_conv<MB2, true>  <<<g2, 256, 0, stream>>>(xyz, c2w1, A, mask, P, CP);
    k_finalize         <<<1, 256, 0, stream>>>(CP, fc2, out);
}

// Round 4
// 48.041 us; speedup vs baseline: 3.0763x; 1.8583x over previous
//
#include <hip/hip_runtime.h>
#include <math.h>

typedef _Float16 f16;
typedef _Float16 f16x4 __attribute__((ext_vector_type(4)));
typedef _Float16 f16x8 __attribute__((ext_vector_type(8)));
typedef float f32x4 __attribute__((ext_vector_type(4)));

#define Bn 2
#define Nn 384
#define Cc 16
#define Hh 64
#define NBk 10
#define NT 64                 // n per conv block (4 waves x 16)
#define NTILES (Nn/NT)        // 6
#define MCH 64                // m-chunks -> 2*6*64 = 768 blocks = 3/CU
#define MB (Nn/MCH)           // 6 m per block
#define SCALE 0.05103103630798288f   // 1/sqrt(384)
#define CP_N (MCH*NTILES*Bn*Cc)      // 12288
#define CKSP 1.1111111111111112f     // RBF center spacing 10/9

__device__ __forceinline__ void gload_lds16(const void* g, void* l) {
    __builtin_amdgcn_global_load_lds((const __attribute__((address_space(1))) unsigned int*)g,
                                     (__attribute__((address_space(3))) unsigned int*)l, 16, 0, 0);
}

// Position of W2x[h][i] inside the per-m fragment tile (A' of stage-2 MFMA):
// frag f = h>>5, lane = ((h>>2)&3)*16 + i, slot j = ((h>>4)&1)*4 + (h&3).
__device__ __forceinline__ int frag_idx(int h, int i) {
    const int f = h >> 5, g = (h >> 2) & 3, j = (((h >> 4) & 1) << 2) | (h & 3);
    return ((f * 64 + g * 16 + i) << 3) | j;
}

// W2x[h][i] = sum_j w2[h][i*16+j] * x_masked[b,m,j]  -> f16 frag-layout tile
__global__ __launch_bounds__(256) void k_w2x_from_x(
    const float* __restrict__ x, const int* __restrict__ mask,
    const float* __restrict__ w2, f16* __restrict__ w2xf)
{
    __shared__ float xs[Cc];
    const int bm = blockIdx.x;           // b*N + m
    const int b = bm / Nn, m = bm % Nn;
    const int tid = threadIdx.x;
    if (tid < Cc) {
        int keep = mask[(size_t)b*Nn*Nn + (size_t)m*Nn + m];
        xs[tid] = keep ? x[(size_t)bm*Cc + tid] : 0.0f;
    }
    __syncthreads();
    const int h = tid >> 2, ig = tid & 3;
    #pragma unroll
    for (int c = 0; c < 4; ++c) {
        const int i = ig*4 + c;
        float acc = 0.f;
        #pragma unroll
        for (int jg = 0; jg < 4; ++jg) {
            float4 wv = *reinterpret_cast<const float4*>(w2 + h*256 + i*16 + jg*4);
            acc += wv.x*xs[jg*4+0] + wv.y*xs[jg*4+1] + wv.z*xs[jg*4+2] + wv.w*xs[jg*4+3];
        }
        w2xf[(size_t)bm*1024 + frag_idx(h, i)] = (f16)acc;
    }
}

// xin[b,m,j] = sum over MCH chunks of f16 partials (conv1 out), then same matmul
__global__ __launch_bounds__(256) void k_w2x_from_part(
    const f16* __restrict__ part, const float* __restrict__ w2, f16* __restrict__ w2xf)
{
    __shared__ float ps[16*16];
    __shared__ float xs[Cc];
    const int bm = blockIdx.x;
    const int b = bm / Nn, m = bm % Nn;
    const int tid = threadIdx.x;
    const int i = tid & 15, g = tid >> 4;   // 16 groups x 4 chunks
    {
        float s = 0.f;
        #pragma unroll
        for (int cc = 0; cc < MCH/16; ++cc) {
            const int ch = g*(MCH/16) + cc;
            s += (float)part[(((size_t)ch*Bn + b)*Nn + m)*Cc + i];
        }
        ps[g*16 + i] = s;
    }
    __syncthreads();
    if (tid < Cc) {
        float s = 0.f;
        #pragma unroll
        for (int gg = 0; gg < 16; ++gg) s += ps[gg*16 + tid];
        xs[tid] = s;
    }
    __syncthreads();
    const int h = tid >> 2, ig = tid & 3;
    #pragma unroll
    for (int c = 0; c < 4; ++c) {
        const int ii = ig*4 + c;
        float acc = 0.f;
        #pragma unroll
        for (int jg = 0; jg < 4; ++jg) {
            float4 wv = *reinterpret_cast<const float4*>(w2 + h*256 + ii*16 + jg*4);
            acc += wv.x*xs[jg*4+0] + wv.y*xs[jg*4+1] + wv.z*xs[jg*4+2] + wv.w*xs[jg*4+3];
        }
        w2xf[(size_t)bm*1024 + frag_idx(h, ii)] = (f16)acc;
    }
}

// Full-MFMA conv. Stage1: hid = rbf @ w1 via 4x mfma_16x16x16_f16 (D in-lane).
// Stage2: acc[i][n] += W2x^T @ swish(hid) via 2x mfma_16x16x32_f16 (hid stays in regs).
template<bool FINAL>
__global__ __launch_bounds__(256, 3) void k_conv(
    const float* __restrict__ xyz, const float* __restrict__ w1,
    const f16* __restrict__ w2xf, const int* __restrict__ mask,
    f16* __restrict__ parth, float* __restrict__ colpart)
{
    __shared__ __align__(16) f16 dbuf[2][1024];   // 4 KB double-buffered A'-tiles
    __shared__ float sred[4][16];

    const int tid = threadIdx.x;
    const int wv = tid >> 6, l = tid & 63;
    const int g = l >> 4, c = l & 15;
    const int b = blockIdx.z, by = blockIdx.y;
    const int n0 = by*NT, m0 = blockIdx.x*MB, ch = blockIdx.x;
    const int n_me = n0 + wv*16 + c;

    const f16* src = w2xf + (size_t)(b*Nn + m0)*1024;
    if (tid < 128)                       // waves 0,1 stage frag f = tid>>6
        gload_lds16(src + tid*8, &dbuf[0][(tid>>6)*512]);

    // stage-1 A-frags: af[t][j] = (k=4g+j)<10 ? w1[k][16t+c] : 0   (w1^T tiles)
    f16x4 af[4];
    #pragma unroll
    for (int t = 0; t < 4; ++t)
        #pragma unroll
        for (int j = 0; j < 4; ++j) {
            const int k = 4*g + j;
            af[t][j] = (f16)((k < NBk) ? w1[k*Hh + 16*t + c] : 0.f);
        }

    const float* xyzb = xyz + (size_t)b*Nn*3;
    const float xn0 = xyzb[n_me*3+0], xn1 = xyzb[n_me*3+1], xn2 = xyzb[n_me*3+2];

    f32x4 acc = {0.f, 0.f, 0.f, 0.f};
    __syncthreads();                      // dbuf[0] ready

    for (int mi = 0; mi < MB; ++mi) {
        if (mi + 1 < MB && tid < 128)     // prefetch next m-tile
            gload_lds16(src + (size_t)(mi+1)*1024 + tid*8, &dbuf[(mi+1)&1][(tid>>6)*512]);

        const float xm0 = xyzb[(m0+mi)*3+0];   // block-uniform -> scalar
        const float xm1 = xyzb[(m0+mi)*3+1];
        const float xm2 = xyzb[(m0+mi)*3+2];
        const float dx = xn0-xm0, dy = xn1-xm1, dz = xn2-xm2;
        const float r = sqrtf(dx*dx + dy*dy + dz*dz + 1e-12f);

        // stage-1 B-frag: rbf[n=c][k=4g+j]
        f16x4 bf;
        #pragma unroll
        for (int j = 0; j < 4; ++j) {
            const float u = r - (float)(4*g + j) * CKSP;
            bf[j] = (f16)__expf(-u*u);
        }

        const f32x4 zero = {0.f, 0.f, 0.f, 0.f};
        f32x4 h2[4];                      // h2[t][r] = hid[n=c][h=16t+4g+r]
        #pragma unroll
        for (int t = 0; t < 4; ++t)
            h2[t] = __builtin_amdgcn_mfma_f32_16x16x16f16(af[t], bf, zero, 0, 0, 0);

        // stage-2 A'-frags (pre-permuted W2x tile)
        const f16x8 a0 = *reinterpret_cast<const f16x8*>(&dbuf[mi&1][l*8]);
        const f16x8 a1 = *reinterpret_cast<const f16x8*>(&dbuf[mi&1][512 + l*8]);

        // swish + pack hid into B'-slots: slot(g,j) <-> h = 16*(2f+(j>>2)) + 4g + (j&3)
        f16x8 bp0, bp1;
        #pragma unroll
        for (int j = 0; j < 8; ++j) {
            const float v0 = h2[j>>2][j&3];
            const float v1 = h2[2 + (j>>2)][j&3];
            bp0[j] = (f16)(v0 * __builtin_amdgcn_rcpf(1.f + __expf(-v0)));
            bp1[j] = (f16)(v1 * __builtin_amdgcn_rcpf(1.f + __expf(-v1)));
        }
        acc = __builtin_amdgcn_mfma_f32_16x16x32_f16(a0, bp0, acc, 0, 0, 0);
        acc = __builtin_amdgcn_mfma_f32_16x16x32_f16(a1, bp1, acc, 0, 0, 0);
        __syncthreads();                  // drains prefetch; protects dbuf reuse
    }

    // D3: lane holds out[i = 4g+r][n = c] in acc[r]
    if (!FINAL) {
        f16x4 pk;
        #pragma unroll
        for (int rr = 0; rr < 4; ++rr) pk[rr] = (f16)(acc[rr] * SCALE);
        *reinterpret_cast<f16x4*>(&parth[(((size_t)ch*Bn + b)*Nn + n_me)*Cc + 4*g]) = pk;
    } else {
        const int keep = mask[((size_t)b*Nn + n_me)*Nn + n_me];
        float vs[4];
        #pragma unroll
        for (int rr = 0; rr < 4; ++rr) vs[rr] = keep ? acc[rr]*SCALE : 0.f;
        #pragma unroll
        for (int d = 1; d < 16; d <<= 1) {
            #pragma unroll
            for (int rr = 0; rr < 4; ++rr) vs[rr] += __shfl_xor(vs[rr], d, 64);
        }
        if (c == 0) {
            #pragma unroll
            for (int rr = 0; rr < 4; ++rr) sred[wv][4*g + rr] = vs[rr];
        }
        __syncthreads();
        if (tid < 16) {
            const float s = sred[0][tid] + sred[1][tid] + sred[2][tid] + sred[3][tid];
            colpart[(((size_t)ch*NTILES + by)*Bn + b)*Cc + tid] = s;
        }
    }
}

// colpart -> colsum -> normalize (ddof=1) -> @fc2^T -> softmax
__global__ __launch_bounds__(256) void k_finalize(
    const float* __restrict__ colpart, const float* __restrict__ fc2, float* __restrict__ out)
{
    __shared__ float redf[1024];
    const int tid = threadIdx.x;
    float4 a; a.x = a.y = a.z = a.w = 0.f;
    for (int base = tid*4; base < CP_N; base += 1024) {
        float4 v = *reinterpret_cast<const float4*>(colpart + base);
        a.x += v.x; a.y += v.y; a.z += v.z; a.w += v.w;
    }
    *reinterpret_cast<float4*>(&redf[tid*4]) = a;
    __syncthreads();
    if (tid < 32) {
        float v = 0.f;                      // flat idx ≡ b*16+i (mod 32)
        #pragma unroll
        for (int k = 0; k < 32; ++k) v += redf[tid + 32*k];
        const int i = tid & 15;             // lanes 0-15: b=0, 16-31: b=1
        float sum = v;
        #pragma unroll
        for (int d = 1; d < 16; d <<= 1) sum += __shfl_xor(sum, d, 32);
        const float mean = sum * (1.0f/16.0f);
        const float c0 = v - mean;
        float vsq = c0*c0;
        #pragma unroll
        for (int d = 1; d < 16; d <<= 1) vsq += __shfl_xor(vsq, d, 32);
        const float nv = c0 / (sqrtf(vsq * (1.0f/15.0f)) + 1e-6f);  // std ddof=1 + eps
        float y = 0.f;
        #pragma unroll
        for (int j = 0; j < 16; ++j) {
            float nj = __shfl(nv, (tid & 16) + j, 32);
            y += nj * fc2[i*16 + j];
        }
        float mx = y;
        #pragma unroll
        for (int d = 1; d < 16; d <<= 1) mx = fmaxf(mx, __shfl_xor(mx, d, 32));
        const float e = __expf(y - mx);
        float es = e;
        #pragma unroll
        for (int d = 1; d < 16; d <<= 1) es += __shfl_xor(es, d, 32);
        out[(tid >> 4)*Cc + i] = e / es;
    }
}

extern "C" void kernel_launch(void* const* d_in, const int* in_sizes, int n_in,
                              void* d_out, int out_size, void* d_ws, size_t ws_size,
                              hipStream_t stream) {
    const float* x    = (const float*)d_in[0];
    const float* xyz  = (const float*)d_in[1];
    const int*   mask = (const int*)  d_in[2];
    const float* c1w1 = (const float*)d_in[3];
    const float* c1w2 = (const float*)d_in[4];
    const float* c2w1 = (const float*)d_in[5];
    const float* c2w2 = (const float*)d_in[6];
    const float* fc2  = (const float*)d_in[7];
    float* out = (float*)d_out;

    f16*   W  = (f16*)d_ws;                              // frag tiles: 768*1024 f16 = 1.5 MB
    f16*   P  = W + (size_t)Bn*Nn*1024;                  // f16 partials: MCH*B*N*C = 1.5 MB
    float* CP = (float*)(P + (size_t)MCH*Bn*Nn*Cc);      // colpart: 12288 f32

    dim3 gconv(MCH, NTILES, Bn);

    k_w2x_from_x    <<<Bn*Nn, 256, 0, stream>>>(x, mask, c1w2, W);
    k_conv<false>   <<<gconv, 256, 0, stream>>>(xyz, c1w1, W, mask, P, CP);
    k_w2x_from_part <<<Bn*Nn, 256, 0, stream>>>(P, c2w2, W);
    k_conv<true>    <<<gconv, 256, 0, stream>>>(xyz, c2w1, W, mask, P, CP);
    k_finalize      <<<1, 256, 0, stream>>>(CP, fc2, out);
}

// Round 5
// 41.416 us; speedup vs baseline: 3.5684x; 1.1600x over previous
//
#include <hip/hip_runtime.h>
#include <math.h>

typedef _Float16 f16;
typedef _Float16 f16x4 __attribute__((ext_vector_type(4)));
typedef _Float16 f16x8 __attribute__((ext_vector_type(8)));
typedef float f32x4 __attribute__((ext_vector_type(4)));

#define Bn 2
#define Nn 384
#define Cc 16
#define Hh 64
#define NBk 10
#define NT 64                 // n per conv block (4 waves x 16)
#define NTILES (Nn/NT)        // 6
#define MCH 64                // m-chunks -> 64*6*2 = 768 blocks = 3/CU
#define MB (Nn/MCH)           // 6 m per block
#define SCALE 0.05103103630798288f   // 1/sqrt(384)
#define CP_N (MCH*NTILES*Bn*Cc)      // 12288
#define CKSP 1.1111111111111112f     // RBF center spacing 10/9

// Position of W2x[h][i] inside the per-m fragment tile (A' of stage-2 MFMA):
// frag f = h>>5, lane = ((h>>2)&3)*16 + i, slot j = ((h>>4)&1)*4 + (h&3).
__device__ __forceinline__ int frag_idx(int h, int i) {
    const int f = h >> 5, g = (h >> 2) & 3, j = (((h >> 4) & 1) << 2) | (h & 3);
    return ((f * 64 + g * 16 + i) << 3) | j;
}

// Fused conv: front A builds xsum[mq][i] (conv1: masked x; conv2: chunk-reduced
// conv1 partials). Front B builds the 6 frag-layout f16 W2x tiles in LDS.
// Main loop: stage1 hid = rbf @ w1 (mfma 16x16x16, D in-lane), stage2
// acc += W2x^T @ swish(hid) (mfma 16x16x32, hid straight from registers).
// FIRST: write f16 partials [b][n][ch][i]. else: mask rows + column-sum -> colpart.
template<bool FIRST>
__global__ __launch_bounds__(256, 3) void k_conv(
    const float* __restrict__ xyz, const float* __restrict__ w1,
    const float* __restrict__ w2, const float* __restrict__ x,
    const f16* __restrict__ pin, const int* __restrict__ mask,
    f16* __restrict__ pout, float* __restrict__ colpart)
{
    __shared__ __align__(16) f16 tiles[MB][1024];   // 12 KB
    __shared__ __align__(16) float xsum[MB][Cc];
    __shared__ float psum[192];
    __shared__ float sred[4][16];

    const int tid = threadIdx.x;
    const int wv = tid >> 6, l = tid & 63;
    const int g = l >> 4, c = l & 15;
    const int b = blockIdx.z, by = blockIdx.y;
    const int n0 = by*NT, m0 = blockIdx.x*MB, ch = blockIdx.x;
    const int n_me = n0 + wv*16 + c;

    // ---- front A: xsum[mq][i] = conv input row for this chunk's m's ----
    if (FIRST) {
        if (tid < MB*Cc) {
            const int mq = tid >> 4, i = tid & 15;
            const int m = m0 + mq;
            const int keep = mask[((size_t)b*Nn + m)*Nn + m];
            xsum[mq][i] = keep ? x[((size_t)b*Nn + m)*Cc + i] : 0.f;
        }
    } else {
        if (tid < 192) {     // (mq,i) pair x half: sum 32 of 64 chunks each
            const int pair = tid >> 1, half = tid & 1;
            const int mq = pair >> 4, i = pair & 15;
            const int m = m0 + mq;
            const f16* p = pin + (((size_t)b*Nn + m)*MCH + half*32)*Cc + i;
            float s = 0.f;
            #pragma unroll
            for (int cc = 0; cc < 32; ++cc) s += (float)p[cc*Cc];
            psum[tid] = s;
        }
        __syncthreads();
        if (tid < MB*Cc) xsum[tid >> 4][tid & 15] = psum[tid*2] + psum[tid*2 + 1];
    }
    __syncthreads();

    // ---- front B: tiles[mq][frag_idx(h,i)] = (f16) sum_j w2[h][i*16+j]*xsum[mq][j]
    {
        const int h = tid >> 2, ig = tid & 3;
        #pragma unroll 1
        for (int cq = 0; cq < 4; ++cq) {
            const int i = ig*4 + cq;
            const float4 wq0 = *reinterpret_cast<const float4*>(w2 + h*256 + i*16 + 0);
            const float4 wq1 = *reinterpret_cast<const float4*>(w2 + h*256 + i*16 + 4);
            const float4 wq2 = *reinterpret_cast<const float4*>(w2 + h*256 + i*16 + 8);
            const float4 wq3 = *reinterpret_cast<const float4*>(w2 + h*256 + i*16 + 12);
            const int fi = frag_idx(h, i);
            #pragma unroll 1
            for (int mq = 0; mq < MB; ++mq) {
                const float4 x0 = *reinterpret_cast<const float4*>(&xsum[mq][0]);
                const float4 x1 = *reinterpret_cast<const float4*>(&xsum[mq][4]);
                const float4 x2 = *reinterpret_cast<const float4*>(&xsum[mq][8]);
                const float4 x3 = *reinterpret_cast<const float4*>(&xsum[mq][12]);
                float a = wq0.x*x0.x + wq0.y*x0.y + wq0.z*x0.z + wq0.w*x0.w
                        + wq1.x*x1.x + wq1.y*x1.y + wq1.z*x1.z + wq1.w*x1.w
                        + wq2.x*x2.x + wq2.y*x2.y + wq2.z*x2.z + wq2.w*x2.w
                        + wq3.x*x3.x + wq3.y*x3.y + wq3.z*x3.z + wq3.w*x3.w;
                tiles[mq][fi] = (f16)a;
            }
        }
    }

    // stage-1 A-frags: af[t][j] = (k=4g+j)<10 ? w1[k][16t+c] : 0   (w1^T tiles)
    f16x4 af[4];
    #pragma unroll
    for (int t = 0; t < 4; ++t)
        #pragma unroll
        for (int j = 0; j < 4; ++j) {
            const int k = 4*g + j;
            af[t][j] = (f16)((k < NBk) ? w1[k*Hh + 16*t + c] : 0.f);
        }

    const float* xyzb = xyz + (size_t)b*Nn*3;
    const float xn0 = xyzb[n_me*3+0], xn1 = xyzb[n_me*3+1], xn2 = xyzb[n_me*3+2];

    f32x4 acc = {0.f, 0.f, 0.f, 0.f};
    __syncthreads();                      // tiles ready; no in-loop barriers

    #pragma unroll
    for (int mi = 0; mi < MB; ++mi) {
        const float xm0 = xyzb[(m0+mi)*3+0];   // block-uniform -> scalar loads
        const float xm1 = xyzb[(m0+mi)*3+1];
        const float xm2 = xyzb[(m0+mi)*3+2];
        const float dx = xn0-xm0, dy = xn1-xm1, dz = xn2-xm2;
        const float r = sqrtf(dx*dx + dy*dy + dz*dz + 1e-12f);

        // stage-1 B-frag: rbf[n=c][k=4g+j]
        f16x4 bf;
        #pragma unroll
        for (int j = 0; j < 4; ++j) {
            const float u = r - (float)(4*g + j) * CKSP;
            bf[j] = (f16)__expf(-u*u);
        }

        const f32x4 zero = {0.f, 0.f, 0.f, 0.f};
        f32x4 h2[4];                      // h2[t][r] = hid[n=c][h=16t+4g+r]
        #pragma unroll
        for (int t = 0; t < 4; ++t)
            h2[t] = __builtin_amdgcn_mfma_f32_16x16x16f16(af[t], bf, zero, 0, 0, 0);

        // stage-2 A'-frags from LDS (pre-permuted W2x tile)
        const f16x8 a0 = *reinterpret_cast<const f16x8*>(&tiles[mi][l*8]);
        const f16x8 a1 = *reinterpret_cast<const f16x8*>(&tiles[mi][512 + l*8]);

        // swish + pack hid into B'-slots: slot(g,j) <-> h = 16*(2f+(j>>2)) + 4g + (j&3)
        f16x8 bp0, bp1;
        #pragma unroll
        for (int j = 0; j < 8; ++j) {
            const float v0 = h2[j>>2][j&3];
            const float v1 = h2[2 + (j>>2)][j&3];
            bp0[j] = (f16)(v0 * __builtin_amdgcn_rcpf(1.f + __expf(-v0)));
            bp1[j] = (f16)(v1 * __builtin_amdgcn_rcpf(1.f + __expf(-v1)));
        }
        acc = __builtin_amdgcn_mfma_f32_16x16x32_f16(a0, bp0, acc, 0, 0, 0);
        acc = __builtin_amdgcn_mfma_f32_16x16x32_f16(a1, bp1, acc, 0, 0, 0);
    }

    // D: lane holds out[i = 4g+r][n = c] in acc[r]
    if (FIRST) {
        f16x4 pk;
        #pragma unroll
        for (int rr = 0; rr < 4; ++rr) pk[rr] = (f16)(acc[rr] * SCALE);
        *reinterpret_cast<f16x4*>(&pout[(((size_t)b*Nn + n_me)*MCH + ch)*Cc + 4*g]) = pk;
    } else {
        const int keep = mask[((size_t)b*Nn + n_me)*Nn + n_me];
        float vs[4];
        #pragma unroll
        for (int rr = 0; rr < 4; ++rr) vs[rr] = keep ? acc[rr]*SCALE : 0.f;
        #pragma unroll
        for (int d = 1; d < 16; d <<= 1) {
            #pragma unroll
            for (int rr = 0; rr < 4; ++rr) vs[rr] += __shfl_xor(vs[rr], d, 64);
        }
        if (c == 0) {
            #pragma unroll
            for (int rr = 0; rr < 4; ++rr) sred[wv][4*g + rr] = vs[rr];
        }
        __syncthreads();
        if (tid < 16) {
            const float s = sred[0][tid] + sred[1][tid] + sred[2][tid] + sred[3][tid];
            colpart[(((size_t)ch*NTILES + by)*Bn + b)*Cc + tid] = s;
        }
    }
}

// colpart -> colsum -> normalize (ddof=1) -> @fc2^T -> softmax
__global__ __launch_bounds__(256) void k_finalize(
    const float* __restrict__ colpart, const float* __restrict__ fc2, float* __restrict__ out)
{
    __shared__ float redf[1024];
    const int tid = threadIdx.x;
    float4 a; a.x = a.y = a.z = a.w = 0.f;
    for (int base = tid*4; base < CP_N; base += 1024) {
        float4 v = *reinterpret_cast<const float4*>(colpart + base);
        a.x += v.x; a.y += v.y; a.z += v.z; a.w += v.w;
    }
    *reinterpret_cast<float4*>(&redf[tid*4]) = a;
    __syncthreads();
    if (tid < 32) {
        float v = 0.f;                      // flat idx ≡ b*16+i (mod 32)
        #pragma unroll
        for (int k = 0; k < 32; ++k) v += redf[tid + 32*k];
        const int i = tid & 15;             // lanes 0-15: b=0, 16-31: b=1
        float sum = v;
        #pragma unroll
        for (int d = 1; d < 16; d <<= 1) sum += __shfl_xor(sum, d, 32);
        const float mean = sum * (1.0f/16.0f);
        const float c0 = v - mean;
        float vsq = c0*c0;
        #pragma unroll
        for (int d = 1; d < 16; d <<= 1) vsq += __shfl_xor(vsq, d, 32);
        const float nv = c0 / (sqrtf(vsq * (1.0f/15.0f)) + 1e-6f);  // std ddof=1 + eps
        float y = 0.f;
        #pragma unroll
        for (int j = 0; j < 16; ++j) {
            float nj = __shfl(nv, (tid & 16) + j, 32);
            y += nj * fc2[i*16 + j];
        }
        float mx = y;
        #pragma unroll
        for (int d = 1; d < 16; d <<= 1) mx = fmaxf(mx, __shfl_xor(mx, d, 32));
        const float e = __expf(y - mx);
        float es = e;
        #pragma unroll
        for (int d = 1; d < 16; d <<= 1) es += __shfl_xor(es, d, 32);
        out[(tid >> 4)*Cc + i] = e / es;
    }
}

extern "C" void kernel_launch(void* const* d_in, const int* in_sizes, int n_in,
                              void* d_out, int out_size, void* d_ws, size_t ws_size,
                              hipStream_t stream) {
    const float* x    = (const float*)d_in[0];
    const float* xyz  = (const float*)d_in[1];
    const int*   mask = (const int*)  d_in[2];
    const float* c1w1 = (const float*)d_in[3];
    const float* c1w2 = (const float*)d_in[4];
    const float* c2w1 = (const float*)d_in[5];
    const float* c2w2 = (const float*)d_in[6];
    const float* fc2  = (const float*)d_in[7];
    float* out = (float*)d_out;

    f16*   P  = (f16*)d_ws;                          // partials [b][n][ch][i]: 1.5 MB
    float* CP = (float*)(P + (size_t)Bn*Nn*MCH*Cc);  // colpart: 12288 f32

    dim3 gconv(MCH, NTILES, Bn);

    k_conv<true>  <<<gconv, 256, 0, stream>>>(xyz, c1w1, c1w2, x, (const f16*)nullptr, mask, P, CP);
    k_conv<false> <<<gconv, 256, 0, stream>>>(xyz, c2w1, c2w2, x, P, mask, (f16*)nullptr, CP);
    k_finalize    <<<1, 256, 0, stream>>>(CP, fc2, out);
}